// Round 13
// baseline (4038.821 us; speedup 1.0000x reference)
//
#include <hip/hip_runtime.h>
#include <hip/hip_bf16.h>
#include <math.h>

// Problem constants: T=256, B=64, I=512, H=512
#define T_LEN 256
#define BATCH 64
#define HSZ   512

typedef __bf16 bf16x8 __attribute__((ext_vector_type(8)));
typedef float  f32x4  __attribute__((ext_vector_type(4)));

// ---------- bf16 helpers ----------
__device__ __forceinline__ unsigned short f2bf_rne(float f) {
    union { float f; unsigned int u; } c; c.f = f;
    unsigned int u = c.u;
    unsigned int r = (u + 0x7fffu + ((u >> 16) & 1u)) >> 16;
    return (unsigned short)r;
}
__device__ __forceinline__ float bf2f(unsigned short h) {
    union { unsigned int u; float f; } c; c.u = ((unsigned int)h) << 16;
    return c.f;
}
__device__ __forceinline__ void split_rne(float v, unsigned short& hi, unsigned short& lo) {
    hi = f2bf_rne(v);
    lo = f2bf_rne(v - bf2f(hi));
}

__device__ __forceinline__ float sigmoid_fast(float x) {
    return 1.0f / (1.0f + __expf(-x));
}
__device__ __forceinline__ float tanh_fast(float x) {
    float e = __expf(2.0f * x);
    return 1.0f - 2.0f / (e + 1.0f);
}

// coherent 16B load (2 x 8B agent-scope relaxed atomics; reads the L3 coherence point)
__device__ __forceinline__ bf16x8 coh16(const unsigned short* p) {
    const unsigned long long* q = (const unsigned long long*)p;
    unsigned long long a = __hip_atomic_load(q,     __ATOMIC_RELAXED, __HIP_MEMORY_SCOPE_AGENT);
    unsigned long long b = __hip_atomic_load(q + 1, __ATOMIC_RELAXED, __HIP_MEMORY_SCOPE_AGENT);
    union { unsigned long long u[2]; bf16x8 v; } c;
    c.u[0] = a; c.u[1] = b;
    return c.v;
}

// ============================================================================
// Layouts (ushort):
//   xf  [t][nt(4)][kc(16)][pl(2)][lane(64)][e(8)]   hi/lo       32 MB
//   h1f [t][nt(4)][kc(32)][lane(64)][e(8)]          single bf16 32 MB
//   st  [par(2)][cell(4)][nt(4)][kc(16)][lane(64)][e(8)] single 512 KB
//   wp  [cell(2)][bu(64)][strip(2)][kc(KC)][lane(64)][e(8)] SINGLE bf16 (round-13)
// B-frag (16x16x32): lane l holds B[col = nt*16 + (l&15)][k = kc*32 + (l>>4)*8 + e]
// A-frag: lane l holds A[pr_g = bu*32 + strip*16 + (l&15)][k = kc*32 + (l>>4)*8 + e],
//   pr_g = unit*4 + gate (gate-interleaved rows)
// Precision: weights single RNE bf16 (adds ~2e-4 preactivation RMS);
//   x hi/lo (2 MFMAs/kc/strip); h/h1 single bf16.
// Geometry: 64 blocks/dir (128 grid), 2 strips/block -> weight VGPR = 64 (L0) /
//   96 (L1) per thread — the round-8-proven residency budget.
// Sync: round-8 scheme (write-through st, vmcnt drain, 64 flat flags/dir).
// ============================================================================

// ---------- pack x into B-frag hi/lo layout ----------
__global__ __launch_bounds__(256)
void pack_x(const float* __restrict__ x, unsigned short* __restrict__ xf) {
    int t = blockIdx.x * 256 + threadIdx.x;       // 4096*256 threads
    int lane = t & 63;
    int id = t >> 6;
    int kc = id & 15; id >>= 4;
    int nt = id & 3;  id >>= 2;
    int tt = id;                                   // 0..255
    int b  = nt * 16 + (lane & 15);
    int k0 = kc * 32 + (lane >> 4) * 8;
    const float* src = x + ((size_t)tt * BATCH + b) * 512 + k0;
    union { unsigned short s[8]; uint4 v; } H, L;
#pragma unroll
    for (int e = 0; e < 8; ++e) split_rne(src[e], H.s[e], L.s[e]);
    size_t base = ((((size_t)tt * 4 + nt) * 16 + kc) * 2) * 512 + (size_t)lane * 8;
    *reinterpret_cast<uint4*>(&xf[base])       = H.v;
    *reinterpret_cast<uint4*>(&xf[base + 512]) = L.v;
}

// ---------- pack weights: single bf16, 64 blocks/dir x 2 strips ----------
template<int KC>   // 32 (L0) or 48 (L1);  DIN = (KC-16)*32
__global__ __launch_bounds__(256)
void pack_w(const float* __restrict__ wih0, const float* __restrict__ whh0,
            const float* __restrict__ wih1, const float* __restrict__ whh1,
            unsigned short* __restrict__ wp) {
    constexpr int DIN = (KC - 16) * 32;
    int t = blockIdx.x * 256 + threadIdx.x;        // 2*64*2*KC*64 threads
    int lane = t & 63;
    int id = t >> 6;
    int kc = id % KC; id /= KC;
    int strip = id & 1; id >>= 1;
    int bu = id & 63; id >>= 6;
    int cell = id;
    if (cell >= 2) return;
    const float* wih = cell ? wih1 : wih0;
    const float* whh = cell ? whh1 : whh0;
    int pr_g = bu * 32 + strip * 16 + (lane & 15);
    int u_g = pr_g >> 2, g = pr_g & 3;
    int row = g * 512 + u_g;
    int k0 = kc * 32 + (lane >> 4) * 8;
    union { unsigned short s[8]; uint4 v; } H;
#pragma unroll
    for (int e = 0; e < 8; ++e) {
        int k = k0 + e;
        float v = (k < DIN) ? wih[(size_t)row * DIN + k]
                            : whh[(size_t)row * 512 + (k - DIN)];
        H.s[e] = f2bf_rne(v);
    }
    size_t base = ((((size_t)cell * 64 + bu) * 2 + strip) * KC + kc) * 512 + (size_t)lane * 8;
    *reinterpret_cast<uint4*>(&wp[base]) = H.v;
}

// ---------- init h-state (parity 0) in single-bf16 frag layout ----------
__global__ __launch_bounds__(256)
void init_state(const float* __restrict__ h0, unsigned short* __restrict__ st) {
    int i = blockIdx.x * 256 + threadIdx.x;       // 4*64*512
    int cell = i >> 15;
    int r = i & 32767;
    int b = r >> 9;
    int u = r & 511;
    unsigned short hh = f2bf_rne(h0[((size_t)cell * BATCH + b) * 512 + u]);
    int nt = b >> 4, kc = u >> 5, rr = u & 31;
    int lane = ((rr >> 3) << 4) | (b & 15);
    int e = rr & 7;
    size_t sb = (((size_t)cell * 4 + nt) * 16 + kc) * 512 + (size_t)lane * 8 + e;
    st[sb] = hh;
}

// ---------- one layer phase: 256 steps, both directions ----------
// Grid: 128 blocks = cd(1bit) x bu(64). Block owns 32 gate-rows (8 units) x 64
// batches as 2 A-strips. 4 waves split K 4-ways (wave w: kc = w + 4*i). Thread
// (w,l): epilogue owns units {bu*8 + w, bu*8 + w + 4}, batch b = l.
template<int DIN>
__global__ __launch_bounds__(256, 1)
void lstm_phase(const unsigned short* __restrict__ bfr,   // xf (L0, hi/lo) or h1f (L1, single)
                const unsigned short* __restrict__ wp,
                const float* __restrict__ bihf, const float* __restrict__ bhhf,
                const float* __restrict__ bihb, const float* __restrict__ bhhb,
                const float* __restrict__ h0, const float* __restrict__ c0,
                const int* __restrict__ lengths,
                unsigned short* __restrict__ st,
                unsigned short* __restrict__ h1f,         // written by L0 (single bf16)
                float* __restrict__ out,                  // written by L1
                unsigned* __restrict__ bar,               // phase region: 2 dirs x 2048 uints
                int cellbase)
{
    constexpr int KC   = (DIN + 512) / 32;   // 32 or 48
    constexpr int KCW  = KC / 4;             // 8 or 12 kc per wave
    constexpr int XCW  = DIN / 128;          // x-kc per wave: 4 or 8
    constexpr int NXKC = DIN / 32;           // 16 or 32
    // per-t input block (ushorts): L0 hi/lo 4*16*2*512 = 65536; L1 single 4*32*512 = 65536
    constexpr size_t TBLK = 65536;

    const int bx = blockIdx.x;
    const int cd = bx & 1;
    const int bu = bx >> 1;                  // [0,64)
    const int cell = cellbase + cd;
    const int tid = threadIdx.x;
    const int w = tid >> 6, l = tid & 63;

    __shared__ float part[4][2][4][16][17];  // [wave][strip][nt][row][col] 34,816 B
    __shared__ float lds_pad[14000];         // +56,000 B -> ~91 KB: forces 1 block/CU

    // keep pad alive without ever executing (lengths[0] is in [1,256])
    if (__builtin_expect(lengths[0] == -2147483647, 0)) {
        lds_pad[tid] = (float)tid;
        __syncthreads();
        if (tid == 0) out[0] = lds_pad[255];
    }

    // flags: flag[bu] at bar + cd*2048 + bu*16 (64B spacing)
    unsigned* flags = bar + (size_t)cd * 2048;

    // ---- persistent weights in registers: 2 strips x KCW single-bf16 frags
    //      = 64 (L0) / 96 (L1) VGPR per thread — the proven residency budget ----
    bf16x8 wreg[2][KCW];
    {
        const unsigned short* wb = wp + (((size_t)cd * 64 + bu) * 2) * KC * 512 + (size_t)l * 8;
#pragma unroll
        for (int m = 0; m < 2; ++m) {
#pragma unroll
            for (int i = 0; i < KCW; ++i) {
                const unsigned short* p = wb + ((size_t)m * KC + (w + 4 * i)) * 512;
                wreg[m][i] = *reinterpret_cast<const bf16x8*>(p);
            }
        }
    }

    // ---- per-thread recurrent state: units {w, w+4} of block, batch b_t = l ----
    const int b_t = l;
    const int len = lengths[b_t];
    const float* bih = cd ? bihb : bihf;
    const float* bhh = cd ? bhhb : bhhf;
    float h_reg[2], c_reg[2], bsum[2][4];
#pragma unroll
    for (int ui = 0; ui < 2; ++ui) {
        int u_g = bu * 8 + w + 4 * ui;
        size_t sidx = ((size_t)cell * BATCH + b_t) * HSZ + u_g;
        h_reg[ui] = h0[sidx];
        c_reg[ui] = c0[sidx];
#pragma unroll
        for (int g = 0; g < 4; ++g)
            bsum[ui][g] = bih[g * 512 + u_g] + bhh[g * 512 + u_g];
    }

    for (int s = 0; s < T_LEN; ++s) {
        const int t = cd ? (T_LEN - 1 - s) : s;
        f32x4 acc[2][4] = {};

        // ---- x-part (no cross-block dependency; runs in the sync shadow) ----
        const unsigned short* bt = bfr + (size_t)t * TBLK;
        if constexpr (DIN == 512) {
            // xf hi/lo: 2 MFMAs/kc/strip (w single, x split)
#pragma unroll
            for (int i = 0; i < XCW; ++i) {
                const int kc = w + 4 * i;
#pragma unroll
                for (int nt = 0; nt < 4; ++nt) {
                    const unsigned short* p = bt + ((size_t)(nt * 16 + kc) * 2) * 512 + (size_t)l * 8;
                    bf16x8 bhi = *reinterpret_cast<const bf16x8*>(p);
                    bf16x8 blo = *reinterpret_cast<const bf16x8*>(p + 512);
#pragma unroll
                    for (int m = 0; m < 2; ++m) {
                        acc[m][nt] = __builtin_amdgcn_mfma_f32_16x16x32_bf16(wreg[m][i], bhi, acc[m][nt], 0, 0, 0);
                        acc[m][nt] = __builtin_amdgcn_mfma_f32_16x16x32_bf16(wreg[m][i], blo, acc[m][nt], 0, 0, 0);
                    }
                }
            }
        } else {
            // h1f single bf16: 1 MFMA/kc/strip
#pragma unroll
            for (int i = 0; i < XCW; ++i) {
                const int kc = w + 4 * i;
#pragma unroll
                for (int nt = 0; nt < 4; ++nt) {
                    const unsigned short* p = bt + (size_t)(nt * 32 + kc) * 512 + (size_t)l * 8;
                    bf16x8 bb = *reinterpret_cast<const bf16x8*>(p);
#pragma unroll
                    for (int m = 0; m < 2; ++m)
                        acc[m][nt] = __builtin_amdgcn_mfma_f32_16x16x32_bf16(wreg[m][i], bb, acc[m][nt], 0, 0, 0);
                }
            }
        }

        // ---- wait for h-state of step s: wave0 polls all 64 flags (1/lane) ----
        if (s > 0) {
            if (tid < 64) {
                const unsigned* f0 = flags + (size_t)tid * 16;
                for (;;) {
                    unsigned a = __hip_atomic_load(f0, __ATOMIC_RELAXED, __HIP_MEMORY_SCOPE_AGENT);
                    if (__all(a >= (unsigned)s)) break;
                    __builtin_amdgcn_s_sleep(1);
                }
            }
            __syncthreads();
        }

        // ---- h-part (single-bf16 coh loads; 8 MB/step aggregate broadcast) ----
        const unsigned short* hb = st + (size_t)((s & 1) * 4 + cell) * 32768;
#pragma unroll
        for (int i = XCW; i < KCW; ++i) {
            const int kch = w + 4 * i - NXKC;
#pragma unroll
            for (int nt = 0; nt < 4; ++nt) {
                const unsigned short* p = hb + (size_t)(nt * 16 + kch) * 512 + (size_t)l * 8;
                bf16x8 bb = coh16(p);
#pragma unroll
                for (int m = 0; m < 2; ++m)
                    acc[m][nt] = __builtin_amdgcn_mfma_f32_16x16x32_bf16(wreg[m][i], bb, acc[m][nt], 0, 0, 0);
            }
        }

        // ---- cross-wave partials ----
#pragma unroll
        for (int m = 0; m < 2; ++m)
#pragma unroll
            for (int nt = 0; nt < 4; ++nt)
#pragma unroll
                for (int j = 0; j < 4; ++j)
                    part[w][m][nt][(l >> 4) * 4 + j][l & 15] = acc[m][nt][j];
        __syncthreads();

        // ---- epilogue: thread (w, l) owns units {w, w+4}, batch b_t ----
        float hv[2];
        const bool mM = (t < len);
#pragma unroll
        for (int ui = 0; ui < 2; ++ui) {
            const int uu = w + 4 * ui;           // unit-in-block 0..7
            float pre[4];
#pragma unroll
            for (int g = 0; g < 4; ++g) {
                int pr = uu * 4 + g;
                int m = pr >> 4, row = pr & 15;
                float ssum = bsum[ui][g];
#pragma unroll
                for (int ww = 0; ww < 4; ++ww)
                    ssum += part[ww][m][b_t >> 4][row][b_t & 15];
                pre[g] = ssum;
            }
            const float gi = sigmoid_fast(pre[0]);
            const float gf = sigmoid_fast(pre[1]);
            const float gg = tanh_fast(pre[2]);
            const float go = sigmoid_fast(pre[3]);
            const float cy = gf * c_reg[ui] + gi * gg;
            const float hy = go * tanh_fast(cy);
            if (mM) { c_reg[ui] = cy; h_reg[ui] = hy; }
            hv[ui] = mM ? hy : 0.f;

            // state write: ONE agent-scope write-through store (single bf16)
            const unsigned short hh = f2bf_rne(h_reg[ui]);
            const int u_g = bu * 8 + uu;
            const int kcs = u_g >> 5, rr = u_g & 31;
            const int lane_t = ((rr >> 3) << 4) | (b_t & 15);
            const int ee = rr & 7;
            size_t sb = (((size_t)(((s + 1) & 1) * 4 + cell) * 4 + (b_t >> 4)) * 16 + kcs) * 512
                      + (size_t)lane_t * 8 + ee;
            __hip_atomic_store(&st[sb], hh, __ATOMIC_RELAXED, __HIP_MEMORY_SCOPE_AGENT);
        }
        // drain this thread's stores to the coherence point, then block-collect
        asm volatile("s_waitcnt vmcnt(0)" ::: "memory");
        __syncthreads();

        // ---- publish: ONE relaxed flag store (no fence, no wbl2) ----
        if (s < T_LEN - 1 && tid == 0) {
            __hip_atomic_store(flags + (size_t)bu * 16, (unsigned)(s + 1),
                               __ATOMIC_RELAXED, __HIP_MEMORY_SCOPE_AGENT);
        }

        // ---- deferred outputs (off the critical path) ----
#pragma unroll
        for (int ui = 0; ui < 2; ++ui) {
            const int u_g = bu * 8 + w + 4 * ui;
            if constexpr (DIN == 512) {
                const unsigned short oh = f2bf_rne(hv[ui]);
                const int k1 = cd * 512 + u_g;
                const int kc1 = k1 >> 5, r1 = k1 & 31;
                const int lane1 = ((r1 >> 3) << 4) | (b_t & 15);
                const int e1 = r1 & 7;
                size_t ob = ((size_t)t * 4 + (b_t >> 4)) * 32 * 512 + (size_t)kc1 * 512
                          + (size_t)lane1 * 8 + e1;
                h1f[ob] = oh;
            } else {
                out[((size_t)t * BATCH + b_t) * 1024 + cd * 512 + u_g] = hv[ui];
            }
        }
    }
}

extern "C" void kernel_launch(void* const* d_in, const int* in_sizes, int n_in,
                              void* d_out, int out_size, void* d_ws, size_t ws_size,
                              hipStream_t stream) {
    const float* x        = (const float*)d_in[0];
    const int*   lengths  = (const int*)d_in[1];
    const float* h0       = (const float*)d_in[2];
    const float* c0       = (const float*)d_in[3];
    const float* w_ih_l0  = (const float*)d_in[4];
    const float* w_hh_l0  = (const float*)d_in[5];
    const float* b_ih_l0  = (const float*)d_in[6];
    const float* b_hh_l0  = (const float*)d_in[7];
    const float* w_ih_l0r = (const float*)d_in[8];
    const float* w_hh_l0r = (const float*)d_in[9];
    const float* b_ih_l0r = (const float*)d_in[10];
    const float* b_hh_l0r = (const float*)d_in[11];
    const float* w_ih_l1  = (const float*)d_in[12];
    const float* w_hh_l1  = (const float*)d_in[13];
    const float* b_ih_l1  = (const float*)d_in[14];
    const float* b_hh_l1  = (const float*)d_in[15];
    const float* w_ih_l1r = (const float*)d_in[16];
    const float* w_hh_l1r = (const float*)d_in[17];
    const float* b_ih_l1r = (const float*)d_in[18];
    const float* b_hh_l1r = (const float*)d_in[19];

    float* out = (float*)d_out;

    // ---- ws carve-up (bytes) ----
    char* base = (char*)d_ws;
    unsigned* bar = (unsigned*)base;                                        // 65,536 B
    unsigned short* st  = (unsigned short*)(base + 65536);                  // 524,288 B
    unsigned short* xf  = (unsigned short*)(base + 65536 + 524288);         // 33,554,432 B
    unsigned short* h1f = (unsigned short*)(base + 65536 + 524288 + 33554432);              // 33,554,432 B
    unsigned short* wp0 = (unsigned short*)(base + 65536 + 524288 + 33554432 + 33554432);   // 8,388,608 B
    unsigned short* wp1 = (unsigned short*)(base + 65536 + 524288 + 33554432 + 33554432 + 8388608); // 12,582,912 B

    hipMemsetAsync(bar, 0, 65536, stream);

    hipLaunchKernelGGL(init_state, dim3(512), dim3(256), 0, stream, h0, st);
    hipLaunchKernelGGL(pack_x, dim3(4096), dim3(256), 0, stream, x, xf);
    hipLaunchKernelGGL((pack_w<32>), dim3(2048), dim3(256), 0, stream,
                       w_ih_l0, w_hh_l0, w_ih_l0r, w_hh_l0r, wp0);
    hipLaunchKernelGGL((pack_w<48>), dim3(3072), dim3(256), 0, stream,
                       w_ih_l1, w_hh_l1, w_ih_l1r, w_hh_l1r, wp1);

    // layer 0: input xf (hi/lo), writes h1f (single bf16); cells 0,1
    hipLaunchKernelGGL((lstm_phase<512>), dim3(128), dim3(256), 0, stream,
                       xf, wp0,
                       b_ih_l0, b_hh_l0, b_ih_l0r, b_hh_l0r,
                       h0, c0, lengths, st, h1f, out, bar, 0);

    // layer 1: input h1f (single bf16), writes out (fp32); cells 2,3
    hipLaunchKernelGGL((lstm_phase<1024>), dim3(128), dim3(256), 0, stream,
                       h1f, wp1,
                       b_ih_l1, b_hh_l1, b_ih_l1r, b_hh_l1r,
                       h0, c0, lengths, st, h1f, out, bar + 8192, 2);
}

// Round 14
// 3638.866 us; speedup vs baseline: 1.1099x; 1.1099x over previous
//
#include <hip/hip_runtime.h>
#include <hip/hip_bf16.h>
#include <math.h>

// Problem constants: T=256, B=64, I=512, H=512
#define T_LEN 256
#define BATCH 64
#define HSZ   512

typedef __bf16 bf16x8 __attribute__((ext_vector_type(8)));
typedef float  f32x4  __attribute__((ext_vector_type(4)));

// ---------- bf16 helpers ----------
__device__ __forceinline__ unsigned short f2bf_rne(float f) {
    union { float f; unsigned int u; } c; c.f = f;
    unsigned int u = c.u;
    unsigned int r = (u + 0x7fffu + ((u >> 16) & 1u)) >> 16;
    return (unsigned short)r;
}
__device__ __forceinline__ float bf2f(unsigned short h) {
    union { unsigned int u; float f; } c; c.u = ((unsigned int)h) << 16;
    return c.f;
}
__device__ __forceinline__ void split_rne(float v, unsigned short& hi, unsigned short& lo) {
    hi = f2bf_rne(v);
    lo = f2bf_rne(v - bf2f(hi));
}

__device__ __forceinline__ float sigmoid_fast(float x) {
    return 1.0f / (1.0f + __expf(-x));
}
__device__ __forceinline__ float tanh_fast(float x) {
    float e = __expf(2.0f * x);
    return 1.0f - 2.0f / (e + 1.0f);
}

// coherent 16B load (2 x 8B agent-scope relaxed atomics; reads the L3 coherence point)
__device__ __forceinline__ bf16x8 coh16(const unsigned short* p) {
    const unsigned long long* q = (const unsigned long long*)p;
    unsigned long long a = __hip_atomic_load(q,     __ATOMIC_RELAXED, __HIP_MEMORY_SCOPE_AGENT);
    unsigned long long b = __hip_atomic_load(q + 1, __ATOMIC_RELAXED, __HIP_MEMORY_SCOPE_AGENT);
    union { unsigned long long u[2]; bf16x8 v; } c;
    c.u[0] = a; c.u[1] = b;
    return c.v;
}

// ============================================================================
// Layouts (ushort):
//   xf  [t][nt(4)][kc(16)][pl(2)][lane(64)][e(8)]   hi/lo       32 MB
//   h1f [t][nt(4)][kc(32)][lane(64)][e(8)]          single bf16 32 MB
//   st  [par(2)][cell(4)][nt(4)][kc(16)][lane(64)][e(8)] single 512 KB
//   wp  [cell(2)][bu(128)][kc(KC)][lane(64)][e(8)]  SINGLE bf16 (round-14)
// B-frag (16x16x32): lane l holds B[col = nt*16 + (l&15)][k = kc*32 + (l>>4)*8 + e]
// A-frag: lane l holds A[pr_g = bu*16 + (l&15)][k = kc*32 + (l>>4)*8 + e],
//   pr_g = unit*4 + gate (gate-interleaved rows)
// Precision: weights single RNE bf16 (round-13 proved absmax unchanged);
//   x hi/lo (2 MFMAs/kc); h/h1 single bf16 (1 MFMA/kc).
// Geometry: round-12 proven best — 128 blocks/dir (256 grid), 16 rows/block.
//   Weight VGPR/thread = 32 (L0) / 48 (L1): far under the residency ceiling.
// Sync: round-8 scheme (write-through st, vmcnt drain, 128 flat flags/dir).
// ============================================================================

// ---------- pack x into B-frag hi/lo layout ----------
__global__ __launch_bounds__(256)
void pack_x(const float* __restrict__ x, unsigned short* __restrict__ xf) {
    int t = blockIdx.x * 256 + threadIdx.x;       // 4096*256 threads
    int lane = t & 63;
    int id = t >> 6;
    int kc = id & 15; id >>= 4;
    int nt = id & 3;  id >>= 2;
    int tt = id;                                   // 0..255
    int b  = nt * 16 + (lane & 15);
    int k0 = kc * 32 + (lane >> 4) * 8;
    const float* src = x + ((size_t)tt * BATCH + b) * 512 + k0;
    union { unsigned short s[8]; uint4 v; } H, L;
#pragma unroll
    for (int e = 0; e < 8; ++e) split_rne(src[e], H.s[e], L.s[e]);
    size_t base = ((((size_t)tt * 4 + nt) * 16 + kc) * 2) * 512 + (size_t)lane * 8;
    *reinterpret_cast<uint4*>(&xf[base])       = H.v;
    *reinterpret_cast<uint4*>(&xf[base + 512]) = L.v;
}

// ---------- pack weights: single bf16, 128 blocks/dir ----------
template<int KC>   // 32 (L0) or 48 (L1);  DIN = (KC-16)*32
__global__ __launch_bounds__(256)
void pack_w(const float* __restrict__ wih0, const float* __restrict__ whh0,
            const float* __restrict__ wih1, const float* __restrict__ whh1,
            unsigned short* __restrict__ wp) {
    constexpr int DIN = (KC - 16) * 32;
    int t = blockIdx.x * 256 + threadIdx.x;        // 2*128*KC*64 threads
    int lane = t & 63;
    int id = t >> 6;
    int kc = id % KC; id /= KC;
    int bu = id & 127; id >>= 7;
    int cell = id;
    if (cell >= 2) return;
    const float* wih = cell ? wih1 : wih0;
    const float* whh = cell ? whh1 : whh0;
    int pr_g = bu * 16 + (lane & 15);
    int u_g = pr_g >> 2, g = pr_g & 3;
    int row = g * 512 + u_g;
    int k0 = kc * 32 + (lane >> 4) * 8;
    union { unsigned short s[8]; uint4 v; } H;
#pragma unroll
    for (int e = 0; e < 8; ++e) {
        int k = k0 + e;
        float v = (k < DIN) ? wih[(size_t)row * DIN + k]
                            : whh[(size_t)row * 512 + (k - DIN)];
        H.s[e] = f2bf_rne(v);
    }
    size_t base = (((size_t)cell * 128 + bu) * KC + kc) * 512 + (size_t)lane * 8;
    *reinterpret_cast<uint4*>(&wp[base]) = H.v;
}

// ---------- init h-state (parity 0) in single-bf16 frag layout ----------
__global__ __launch_bounds__(256)
void init_state(const float* __restrict__ h0, unsigned short* __restrict__ st) {
    int i = blockIdx.x * 256 + threadIdx.x;       // 4*64*512
    int cell = i >> 15;
    int r = i & 32767;
    int b = r >> 9;
    int u = r & 511;
    unsigned short hh = f2bf_rne(h0[((size_t)cell * BATCH + b) * 512 + u]);
    int nt = b >> 4, kc = u >> 5, rr = u & 31;
    int lane = ((rr >> 3) << 4) | (b & 15);
    int e = rr & 7;
    size_t sb = (((size_t)cell * 4 + nt) * 16 + kc) * 512 + (size_t)lane * 8 + e;
    st[sb] = hh;
}

// ---------- one layer phase: 256 steps, both directions ----------
// Grid: 256 blocks = cd(1bit) x bu(128). Block owns 16 gate-rows (4 units) x 64 batches.
// 4 waves split K 4-ways (wave w: kc = w + 4*i). Thread (w,l): epilogue owns
// (unit u_g = bu*4 + w, batch b = l).
template<int DIN>
__global__ __launch_bounds__(256, 1)
void lstm_phase(const unsigned short* __restrict__ bfr,   // xf (L0, hi/lo) or h1f (L1, single)
                const unsigned short* __restrict__ wp,
                const float* __restrict__ bihf, const float* __restrict__ bhhf,
                const float* __restrict__ bihb, const float* __restrict__ bhhb,
                const float* __restrict__ h0, const float* __restrict__ c0,
                const int* __restrict__ lengths,
                unsigned short* __restrict__ st,
                unsigned short* __restrict__ h1f,         // written by L0 (single bf16)
                float* __restrict__ out,                  // written by L1
                unsigned* __restrict__ bar,               // phase region: 2 dirs x 2048 uints
                int cellbase)
{
    constexpr int KC   = (DIN + 512) / 32;   // 32 or 48
    constexpr int KCW  = KC / 4;             // 8 or 12 kc per wave
    constexpr int XCW  = DIN / 128;          // x-kc per wave: 4 or 8
    constexpr int NXKC = DIN / 32;           // 16 or 32
    // per-t input block (ushorts): L0 hi/lo 4*16*2*512; L1 single 4*32*512 (both 65536)
    constexpr size_t TBLK = 65536;

    const int bx = blockIdx.x;
    const int cd = bx & 1;
    const int bu = bx >> 1;                  // [0,128)
    const int cell = cellbase + cd;
    const int tid = threadIdx.x;
    const int w = tid >> 6, l = tid & 63;

    __shared__ float part[4][4][16][17];     // 17,408 B
    __shared__ float lds_pad[18000];         // +72,000 B -> ~89 KB: forces 1 block/CU

    // keep pad alive without ever executing (lengths[0] is in [1,256])
    if (__builtin_expect(lengths[0] == -2147483647, 0)) {
        lds_pad[tid] = (float)tid;
        __syncthreads();
        if (tid == 0) out[0] = lds_pad[255];
    }

    // flags: flag[bu] at bar + cd*2048 + bu*16 (64B spacing)
    unsigned* flags = bar + (size_t)cd * 2048;

    // ---- persistent weights in registers: KCW single-bf16 frags
    //      = 32 (L0) / 48 (L1) VGPR per thread — far under residency ceiling ----
    bf16x8 wreg[KCW];
    {
        const unsigned short* wb = wp + ((size_t)cd * 128 + bu) * KC * 512 + (size_t)l * 8;
#pragma unroll
        for (int i = 0; i < KCW; ++i) {
            wreg[i] = *reinterpret_cast<const bf16x8*>(wb + (size_t)(w + 4 * i) * 512);
        }
    }

    // ---- per-thread recurrent state: unit u_g = bu*4 + w, batch b_t = l ----
    const int b_t = l;
    const int u_g = bu * 4 + w;
    const int len = lengths[b_t];
    const float* bih = cd ? bihb : bihf;
    const float* bhh = cd ? bhhb : bhhf;
    const size_t sidx = ((size_t)cell * BATCH + b_t) * HSZ + u_g;
    float h_reg = h0[sidx];
    float c_reg = c0[sidx];
    float bsum[4];
#pragma unroll
    for (int g = 0; g < 4; ++g) bsum[g] = bih[g * 512 + u_g] + bhh[g * 512 + u_g];

    for (int s = 0; s < T_LEN; ++s) {
        const int t = cd ? (T_LEN - 1 - s) : s;
        f32x4 acc[4] = {};

        // ---- x-part (no cross-block dependency; runs in the sync shadow) ----
        const unsigned short* bt = bfr + (size_t)t * TBLK;
        if constexpr (DIN == 512) {
            // xf hi/lo: 2 MFMAs/kc (single w x split x)
#pragma unroll
            for (int i = 0; i < XCW; ++i) {
                const int kc = w + 4 * i;
#pragma unroll
                for (int nt = 0; nt < 4; ++nt) {
                    const unsigned short* p = bt + ((size_t)(nt * 16 + kc) * 2) * 512 + (size_t)l * 8;
                    bf16x8 bhi = *reinterpret_cast<const bf16x8*>(p);
                    bf16x8 blo = *reinterpret_cast<const bf16x8*>(p + 512);
                    acc[nt] = __builtin_amdgcn_mfma_f32_16x16x32_bf16(wreg[i], bhi, acc[nt], 0, 0, 0);
                    acc[nt] = __builtin_amdgcn_mfma_f32_16x16x32_bf16(wreg[i], blo, acc[nt], 0, 0, 0);
                }
            }
        } else {
            // h1f single bf16: 1 MFMA/kc
#pragma unroll
            for (int i = 0; i < XCW; ++i) {
                const int kc = w + 4 * i;
#pragma unroll
                for (int nt = 0; nt < 4; ++nt) {
                    const unsigned short* p = bt + (size_t)(nt * 32 + kc) * 512 + (size_t)l * 8;
                    bf16x8 bb = *reinterpret_cast<const bf16x8*>(p);
                    acc[nt] = __builtin_amdgcn_mfma_f32_16x16x32_bf16(wreg[i], bb, acc[nt], 0, 0, 0);
                }
            }
        }

        // ---- wait for h-state of step s: wave0 polls all 128 flags (2/lane) ----
        if (s > 0) {
            if (tid < 64) {
                const unsigned* f0 = flags + (size_t)tid * 16;
                const unsigned* f1 = flags + (size_t)(tid + 64) * 16;
                for (;;) {
                    unsigned a = __hip_atomic_load(f0, __ATOMIC_RELAXED, __HIP_MEMORY_SCOPE_AGENT);
                    unsigned b = __hip_atomic_load(f1, __ATOMIC_RELAXED, __HIP_MEMORY_SCOPE_AGENT);
                    if (__all(a >= (unsigned)s && b >= (unsigned)s)) break;
                    __builtin_amdgcn_s_sleep(1);
                }
            }
            __syncthreads();
        }

        // ---- h-part (single-bf16 coh loads, 1 MFMA/kc) ----
        const unsigned short* hb = st + (size_t)((s & 1) * 4 + cell) * 32768;
#pragma unroll
        for (int i = XCW; i < KCW; ++i) {
            const int kch = w + 4 * i - NXKC;
#pragma unroll
            for (int nt = 0; nt < 4; ++nt) {
                const unsigned short* p = hb + (size_t)(nt * 16 + kch) * 512 + (size_t)l * 8;
                bf16x8 bb = coh16(p);
                acc[nt] = __builtin_amdgcn_mfma_f32_16x16x32_bf16(wreg[i], bb, acc[nt], 0, 0, 0);
            }
        }

        // ---- cross-wave partials ----
#pragma unroll
        for (int nt = 0; nt < 4; ++nt)
#pragma unroll
            for (int j = 0; j < 4; ++j)
                part[w][nt][(l >> 4) * 4 + j][l & 15] = acc[nt][j];
        __syncthreads();

        // ---- epilogue: thread (w, l) owns unit u_g, batch b_t ----
        float pre[4];
#pragma unroll
        for (int g = 0; g < 4; ++g) {
            float ssum = bsum[g];
#pragma unroll
            for (int ww = 0; ww < 4; ++ww)
                ssum += part[ww][b_t >> 4][w * 4 + g][b_t & 15];
            pre[g] = ssum;
        }
        const float gi = sigmoid_fast(pre[0]);
        const float gf = sigmoid_fast(pre[1]);
        const float gg = tanh_fast(pre[2]);
        const float go = sigmoid_fast(pre[3]);
        const float cy = gf * c_reg + gi * gg;
        const float hy = go * tanh_fast(cy);
        const bool mM = (t < len);
        if (mM) { c_reg = cy; h_reg = hy; }

        // ---- state write: ONE agent-scope write-through store (single bf16) ----
        {
            const unsigned short hh = f2bf_rne(h_reg);
            const int kcs = u_g >> 5, rr = u_g & 31;
            const int lane_t = ((rr >> 3) << 4) | (b_t & 15);
            const int ee = rr & 7;
            size_t sb = (((size_t)(((s + 1) & 1) * 4 + cell) * 4 + (b_t >> 4)) * 16 + kcs) * 512
                      + (size_t)lane_t * 8 + ee;
            __hip_atomic_store(&st[sb], hh, __ATOMIC_RELAXED, __HIP_MEMORY_SCOPE_AGENT);
        }
        // drain this thread's stores to the coherence point, then block-collect
        asm volatile("s_waitcnt vmcnt(0)" ::: "memory");
        __syncthreads();

        // ---- publish: ONE relaxed flag store (no fence, no wbl2) ----
        if (s < T_LEN - 1 && tid == 0) {
            __hip_atomic_store(flags + (size_t)bu * 16, (unsigned)(s + 1),
                               __ATOMIC_RELAXED, __HIP_MEMORY_SCOPE_AGENT);
        }

        // ---- deferred outputs (off the critical path) ----
        const float ov = mM ? hy : 0.f;
        if constexpr (DIN == 512) {
            const unsigned short oh = f2bf_rne(ov);
            const int k1 = cd * 512 + u_g;
            const int kc1 = k1 >> 5, r1 = k1 & 31;
            const int lane1 = ((r1 >> 3) << 4) | (b_t & 15);
            const int e1 = r1 & 7;
            size_t ob = ((size_t)t * 4 + (b_t >> 4)) * 32 * 512 + (size_t)kc1 * 512
                      + (size_t)lane1 * 8 + e1;
            h1f[ob] = oh;
        } else {
            out[((size_t)t * BATCH + b_t) * 1024 + cd * 512 + u_g] = ov;
        }
    }
}

extern "C" void kernel_launch(void* const* d_in, const int* in_sizes, int n_in,
                              void* d_out, int out_size, void* d_ws, size_t ws_size,
                              hipStream_t stream) {
    const float* x        = (const float*)d_in[0];
    const int*   lengths  = (const int*)d_in[1];
    const float* h0       = (const float*)d_in[2];
    const float* c0       = (const float*)d_in[3];
    const float* w_ih_l0  = (const float*)d_in[4];
    const float* w_hh_l0  = (const float*)d_in[5];
    const float* b_ih_l0  = (const float*)d_in[6];
    const float* b_hh_l0  = (const float*)d_in[7];
    const float* w_ih_l0r = (const float*)d_in[8];
    const float* w_hh_l0r = (const float*)d_in[9];
    const float* b_ih_l0r = (const float*)d_in[10];
    const float* b_hh_l0r = (const float*)d_in[11];
    const float* w_ih_l1  = (const float*)d_in[12];
    const float* w_hh_l1  = (const float*)d_in[13];
    const float* b_ih_l1  = (const float*)d_in[14];
    const float* b_hh_l1  = (const float*)d_in[15];
    const float* w_ih_l1r = (const float*)d_in[16];
    const float* w_hh_l1r = (const float*)d_in[17];
    const float* b_ih_l1r = (const float*)d_in[18];
    const float* b_hh_l1r = (const float*)d_in[19];

    float* out = (float*)d_out;

    // ---- ws carve-up (bytes) ----
    char* base = (char*)d_ws;
    unsigned* bar = (unsigned*)base;                                        // 65,536 B
    unsigned short* st  = (unsigned short*)(base + 65536);                  // 524,288 B
    unsigned short* xf  = (unsigned short*)(base + 65536 + 524288);         // 33,554,432 B
    unsigned short* h1f = (unsigned short*)(base + 65536 + 524288 + 33554432);              // 33,554,432 B
    unsigned short* wp0 = (unsigned short*)(base + 65536 + 524288 + 33554432 + 33554432);   // 8,388,608 B
    unsigned short* wp1 = (unsigned short*)(base + 65536 + 524288 + 33554432 + 33554432 + 8388608); // 12,582,912 B

    hipMemsetAsync(bar, 0, 65536, stream);

    hipLaunchKernelGGL(init_state, dim3(512), dim3(256), 0, stream, h0, st);
    hipLaunchKernelGGL(pack_x, dim3(4096), dim3(256), 0, stream, x, xf);
    hipLaunchKernelGGL((pack_w<32>), dim3(2048), dim3(256), 0, stream,
                       w_ih_l0, w_hh_l0, w_ih_l0r, w_hh_l0r, wp0);
    hipLaunchKernelGGL((pack_w<48>), dim3(3072), dim3(256), 0, stream,
                       w_ih_l1, w_hh_l1, w_ih_l1r, w_hh_l1r, wp1);

    // layer 0: input xf (hi/lo), writes h1f (single bf16); cells 0,1
    hipLaunchKernelGGL((lstm_phase<512>), dim3(256), dim3(256), 0, stream,
                       xf, wp0,
                       b_ih_l0, b_hh_l0, b_ih_l0r, b_hh_l0r,
                       h0, c0, lengths, st, h1f, out, bar, 0);

    // layer 1: input h1f (single bf16), writes out (fp32); cells 2,3
    hipLaunchKernelGGL((lstm_phase<1024>), dim3(256), dim3(256), 0, stream,
                       h1f, wp1,
                       b_ih_l1, b_hh_l1, b_ih_l1r, b_hh_l1r,
                       h0, c0, lengths, st, h1f, out, bar + 8192, 2);
}